// Round 16
// baseline (5689.478 us; speedup 1.0000x reference)
//
#include <hip/hip_runtime.h>

// ---- static config (mirrors reference) ----
#define BB   2
#define NN   8192
#define KNN  40
#define SENT 8192
#define G0   17          // subsample grid for dl=0.06
#define G1   9           // for dl=0.12
#define G0_3 (G0*G0*G0)  // 4913
#define G1_3 (G1*G1*G1)  // 729

// ball-query cell grids (cell = r * 1.002, search +-1 cell)
#define GA   14
#define GB   7
#define GC   4
#define G3A  (GA*GA*GA)  // 2744
#define G3B  (GB*GB*GB)  // 343
#define G3C  (GC*GC*GC)  // 64

// d2 exactly as numpy: (dx*dx + dy*dy) + dz*dz, no FMA contraction  [LOCKED]
__device__ __forceinline__ float sqdist(float qx, float qy, float qz,
                                        float sx, float sy, float sz) {
    float dx = __fsub_rn(qx, sx);
    float dy = __fsub_rn(qy, sy);
    float dz = __fsub_rn(qz, sz);
    return __fadd_rn(__fadd_rn(__fmul_rn(dx, dx), __fmul_rn(dy, dy)),
                     __fmul_rn(dz, dz));
}

// prep: copy pts -> out_points[0], fill layer-2 pool/up with SENTINEL, len[0]
__global__ void prep_kernel(const float* __restrict__ pts, float* __restrict__ dout) {
    const size_t PN = (size_t)BB * NN * 3;
    const size_t IN = (size_t)BB * NN * KNN;
    float* out_points0 = dout;
    float* out_pool2   = dout + 3 * PN + 3 * IN + 2 * IN;
    float* out_up2     = dout + 3 * PN + 6 * IN + 2 * IN;
    float* out_len     = dout + 3 * PN + 9 * IN;
    int i = blockIdx.x * 256 + threadIdx.x;
    if (i < (int)PN) out_points0[i] = pts[i];
    if (i < (int)IN) {
        out_pool2[i] = (float)SENT;
        out_up2[i]   = (float)SENT;
    }
    if (i == 0) { out_len[0] = (float)NN; out_len[1] = (float)NN; }
}

// ---- cell-grid build: histogram -> prefix scan -> scatter ----
__global__ void gcount_kernel(const float* __restrict__ pts,
                              const int* __restrict__ len_ptr, int len_const,
                              int* __restrict__ cid, int* __restrict__ hist,
                              float cell, int G) {
    int b = blockIdx.y;
    int i = blockIdx.x * 256 + threadIdx.x;
    int len = len_ptr ? len_ptr[b] : len_const;
    if (i >= len) return;
    const float* p = pts + ((size_t)b * NN + i) * 3;
    int cx = min(max((int)floorf(__fdiv_rn(p[0], cell)), 0), G - 1);
    int cy = min(max((int)floorf(__fdiv_rn(p[1], cell)), 0), G - 1);
    int cz = min(max((int)floorf(__fdiv_rn(p[2], cell)), 0), G - 1);
    int c = (cx * G + cy) * G + cz;
    cid[(size_t)b * NN + i] = c;
    atomicAdd(&hist[(size_t)b * (G * G * G) + c], 1);
}

__global__ __launch_bounds__(1024) void gscan_kernel(
    const int* __restrict__ hist, int* __restrict__ cellStart,
    int* __restrict__ cursor, int G3) {
    __shared__ int wsum[16];
    int b = blockIdx.x;
    int t = threadIdx.x;
    int per = (G3 + 1023) >> 10;
    int start = t * per; if (start > G3) start = G3;
    int end = min(start + per, G3);
    int c = 0;
    for (int v = start; v < end; ++v) c += hist[(size_t)b * G3 + v];
    int lane = t & 63, wid = t >> 6;
    int inc = c;
    for (int d = 1; d < 64; d <<= 1) {
        int u = __shfl_up(inc, d);
        if (lane >= d) inc += u;
    }
    if (lane == 63) wsum[wid] = inc;
    __syncthreads();
    if (t < 16) {
        int wv = wsum[t];
        for (int d = 1; d < 16; d <<= 1) {
            int u = __shfl_up(wv, d);
            if (t >= d) wv += u;
        }
        wsum[t] = wv;
    }
    __syncthreads();
    int excl = inc - c + (wid ? wsum[wid - 1] : 0);
    int run = excl;
    for (int v = start; v < end; ++v) {
        cellStart[(size_t)b * (G3 + 1) + v] = run;
        cursor[(size_t)b * G3 + v] = run;
        run += hist[(size_t)b * G3 + v];
    }
    if (t == 0) cellStart[(size_t)b * (G3 + 1) + G3] = wsum[15];
}

__global__ void gscatter_kernel(const float* __restrict__ pts,
                                const int* __restrict__ len_ptr, int len_const,
                                const int* __restrict__ cid, int* __restrict__ cursor,
                                float4* __restrict__ sorted, int G3) {
    int b = blockIdx.y;
    int i = blockIdx.x * 256 + threadIdx.x;
    int len = len_ptr ? len_ptr[b] : len_const;
    if (i >= len) return;
    int c = cid[(size_t)b * NN + i];
    int pos = atomicAdd(&cursor[(size_t)b * G3 + c], 1);
    const float* p = pts + ((size_t)b * NN + i) * 3;
    sorted[(size_t)b * NN + pos] = make_float4(p[0], p[1], p[2], __int_as_float(i));
}

// radius ball query over cell grid. Selection is by TOTAL ORDER (d2, idx):
// provably identical (set AND order) to the stable ascending-index scan that
// validated bit-exact in R14/R15, for ANY candidate enumeration order.
__global__ __launch_bounds__(64) void bqg_kernel(
    const float* __restrict__ qpts, const float4* __restrict__ sorted,
    const int* __restrict__ cellStart,
    const int* __restrict__ qlen_ptr, int qlen_const,
    float cell, int G, float* __restrict__ out, float r2) {
    __shared__ float d2l[KNN][64];
    __shared__ int   idl[KNN][64];
    int b = blockIdx.y;
    int lane = threadIdx.x;
    int qi = blockIdx.x * 64 + lane;
    int qlen = qlen_ptr ? qlen_ptr[b] : qlen_const;
    bool qvalid = qi < qlen;
    int G3 = G * G * G;
    const int* cs = cellStart + (size_t)b * (G3 + 1);
    const float4* sp = sorted + (size_t)b * NN;
    int cnt = 0;
    if (qvalid) {
        const float* qp = qpts + ((size_t)b * NN + qi) * 3;
        float qx = qp[0], qy = qp[1], qz = qp[2];
        int cx = min(max((int)floorf(__fdiv_rn(qx, cell)), 0), G - 1);
        int cy = min(max((int)floorf(__fdiv_rn(qy, cell)), 0), G - 1);
        int cz = min(max((int)floorf(__fdiv_rn(qz, cell)), 0), G - 1);
        float worstd = 3.4e38f;
        int   worsti = 0x7fffffff;
        int x0 = max(cx - 1, 0), x1 = min(cx + 1, G - 1);
        int y0 = max(cy - 1, 0), y1 = min(cy + 1, G - 1);
        int z0 = max(cz - 1, 0), z1 = min(cz + 1, G - 1);
        for (int x = x0; x <= x1; ++x) {
            for (int y = y0; y <= y1; ++y) {
                int rowc = (x * G + y) * G;
                int s = cs[rowc + z0];
                int e = cs[rowc + z1 + 1];
                for (int i = s; i < e; ++i) {
                    float4 p = sp[i];
                    float d2 = sqdist(qx, qy, qz, p.x, p.y, p.z);
                    if (d2 > r2) continue;                  // inclusive (<= r2) [LOCKED]
                    int nid = __float_as_int(p.w);
                    if (cnt == KNN &&
                        (d2 > worstd || (d2 == worstd && nid > worsti))) continue;
                    int pos = (cnt < KNN) ? cnt : (KNN - 1);
                    while (pos > 0 && (d2l[pos - 1][lane] > d2 ||
                           (d2l[pos - 1][lane] == d2 && idl[pos - 1][lane] > nid))) {
                        d2l[pos][lane] = d2l[pos - 1][lane];
                        idl[pos][lane] = idl[pos - 1][lane];
                        --pos;
                    }
                    d2l[pos][lane] = d2;
                    idl[pos][lane] = nid;
                    if (cnt < KNN) ++cnt;
                    if (cnt == KNN) {
                        worstd = d2l[KNN - 1][lane];
                        worsti = idl[KNN - 1][lane];
                    }
                }
            }
        }
    }
    float* op = out + ((size_t)b * NN + qi) * KNN;
    for (int k = 0; k < KNN; ++k)
        op[k] = (qvalid && k < cnt) ? (float)idl[k][lane] : (float)SENT;
}

// per-point voxel id for subsampling (f32 division, f32 dl)  [LOCKED]
__global__ void vid_kernel(const float* __restrict__ pts,
                           const int* __restrict__ len_ptr, int len_const,
                           int* __restrict__ vid, float dlf, int G) {
    int b = blockIdx.y;
    int i = blockIdx.x * 256 + threadIdx.x;
    int len = len_ptr ? len_ptr[b] : len_const;
    if (i >= len) return;
    const float* p = pts + ((size_t)b * NN + i) * 3;
    int cx = (int)floorf(__fdiv_rn(p[0], dlf));
    int cy = (int)floorf(__fdiv_rn(p[1], dlf));
    int cz = (int)floorf(__fdiv_rn(p[2], dlf));
    cx = min(max(cx, 0), G - 1);
    cy = min(max(cy, 0), G - 1);
    cz = min(max(cz, 0), G - 1);
    vid[(size_t)b * NN + i] = (cx * G + cy) * G + cz;  // lexicographic == ref key order
}

// deterministic per-voxel accumulation: ascending index order, f32 adds [LOCKED]
__global__ __launch_bounds__(256) void vscan_kernel(
    const float* __restrict__ pts, const int* __restrict__ vid,
    const int* __restrict__ len_ptr, int len_const,
    float* __restrict__ vsum, int* __restrict__ vcnt, int G3) {
    __shared__ int svid[NN];
    int b = blockIdx.y;
    int t = threadIdx.x;
    int len = len_ptr ? len_ptr[b] : len_const;
    const int* vb = vid + (size_t)b * NN;
    for (int i = t; i < len; i += 256) svid[i] = vb[i];
    __syncthreads();
    int v = blockIdx.x * 256 + t;
    if (v >= G3) return;
    float sx = 0.f, sy = 0.f, sz = 0.f;
    int c = 0;
    const float* pb = pts + (size_t)b * NN * 3;
    for (int i = 0; i < len; ++i) {
        if (svid[i] == v) {
            sx = __fadd_rn(sx, pb[i * 3]);
            sy = __fadd_rn(sy, pb[i * 3 + 1]);
            sz = __fadd_rn(sz, pb[i * 3 + 2]);
            ++c;
        }
    }
    size_t o = (size_t)b * G3 + v;
    vsum[o * 3]     = sx;
    vsum[o * 3 + 1] = sy;
    vsum[o * 3 + 2] = sz;
    vcnt[o] = c;
}

// compact occupied voxels in key order -> padded means + length.
// MEAN = sum * __frcp_rn(cnt) (reciprocal-multiply) — matches np reference
// bit-exact (verified R14). DO NOT change to true division.  [LOCKED]
__global__ __launch_bounds__(1024) void compact_kernel(
    const float* __restrict__ vsum, const int* __restrict__ vcnt, int G3,
    float* __restrict__ out_pts, int* __restrict__ len_dev,
    float* __restrict__ len_out_f) {
    __shared__ int wsum[16];
    int b = blockIdx.x;
    int t = threadIdx.x;
    int per = (G3 + 1023) >> 10;
    int start = t * per;
    int end = min(start + per, G3);
    if (start > G3) start = G3;
    int c = 0;
    for (int v = start; v < end; ++v) c += (vcnt[(size_t)b * G3 + v] > 0);
    int lane = t & 63, wid = t >> 6;
    int inc = c;
    for (int d = 1; d < 64; d <<= 1) {
        int u = __shfl_up(inc, d);
        if (lane >= d) inc += u;
    }
    if (lane == 63) wsum[wid] = inc;
    __syncthreads();
    if (t < 16) {
        int wv = wsum[t];
        for (int d = 1; d < 16; d <<= 1) {
            int u = __shfl_up(wv, d);
            if (t >= d) wv += u;
        }
        wsum[t] = wv;
    }
    __syncthreads();
    int excl = inc - c + (wid ? wsum[wid - 1] : 0);
    int total = wsum[15];
    int off = excl;
    for (int v = start; v < end; ++v) {
        int cn = vcnt[(size_t)b * G3 + v];
        if (cn > 0) {
            float rinv = __frcp_rn((float)cn);
            const float* sp = vsum + ((size_t)b * G3 + v) * 3;
            float* op = out_pts + ((size_t)b * NN + off) * 3;
            op[0] = __fmul_rn(sp[0], rinv);
            op[1] = __fmul_rn(sp[1], rinv);
            op[2] = __fmul_rn(sp[2], rinv);
            ++off;
        }
    }
    for (int r = total + t; r < NN; r += 1024) {
        float* op = out_pts + ((size_t)b * NN + r) * 3;
        op[0] = 0.f; op[1] = 0.f; op[2] = 0.f;
    }
    if (t == 0) {
        len_dev[b] = total;
        len_out_f[b] = (float)total;
    }
}

extern "C" void kernel_launch(void* const* d_in, const int* in_sizes, int n_in,
                              void* d_out, int out_size, void* d_ws, size_t ws_size,
                              hipStream_t stream) {
    const float* pts = (const float*)d_in[0];
    float* dout = (float*)d_out;
    const size_t PN = (size_t)BB * NN * 3;     // 49152
    const size_t IN = (size_t)BB * NN * KNN;   // 655360
    float* out_points = dout;
    float* out_neigh  = dout + 3 * PN;
    float* out_pool   = out_neigh + 3 * IN;
    float* out_up     = out_pool + 3 * IN;
    float* out_len    = out_up + 3 * IN;
    float* pts1 = out_points + PN;       // layer-1 points live directly in d_out
    float* pts2 = out_points + 2 * PN;

    // workspace layout (float4 arrays first for 16B alignment)
    float4* sortedA = (float4*)d_ws;                         // BB*NN
    float4* sortedB = sortedA + (size_t)BB * NN;
    float4* sortedC = sortedB + (size_t)BB * NN;
    int* histA = (int*)(sortedC + (size_t)BB * NN);          // BB*G3A  (memset 0)
    int* histB = histA + (size_t)BB * G3A;                   // BB*G3B  (memset 0)
    int* histC = histB + (size_t)BB * G3B;                   // BB*G3C  (memset 0)
    int* csA   = histC + (size_t)BB * G3C;                   // BB*(G3A+1)
    int* csB   = csA + (size_t)BB * (G3A + 1);
    int* csC   = csB + (size_t)BB * (G3B + 1);
    int* curA  = csC + (size_t)BB * (G3C + 1);
    int* curB  = curA + (size_t)BB * G3A;
    int* curC  = curB + (size_t)BB * G3B;
    int* cidA  = curC + (size_t)BB * G3C;                    // BB*NN
    int* cidB  = cidA + (size_t)BB * NN;
    int* cidC  = cidB + (size_t)BB * NN;
    int* vid0  = cidC + (size_t)BB * NN;                     // BB*NN
    int* vid1  = vid0 + (size_t)BB * NN;
    float* vsum0 = (float*)(vid1 + (size_t)BB * NN);         // BB*G0_3*3
    int*   vcnt0 = (int*)(vsum0 + (size_t)BB * G0_3 * 3);
    float* vsum1 = (float*)(vcnt0 + (size_t)BB * G0_3);
    int*   vcnt1 = (int*)(vsum1 + (size_t)BB * G1_3 * 3);
    int*   len1  = vcnt1 + (size_t)BB * G1_3;
    int*   len2  = len1 + BB;

    // mirror Python f64 scalar chain, narrow to f32 [LOCKED]
    double r_normal = 0.03 * 2.5;                 // 0.075
    double r0 = r_normal;
    double dl0 = 2.0 * r_normal / 2.5;            // 0.06
    float r2_0   = (float)(r0 * r0);
    float r2_up0 = (float)((2.0 * r0) * (2.0 * r0));
    float dlf0   = (float)dl0;
    r_normal *= 2.0;                              // 0.15
    double r1 = r_normal;
    double dl1 = 2.0 * r_normal / 2.5;            // 0.12
    float r2_1   = (float)(r1 * r1);
    float r2_up1 = (float)((2.0 * r1) * (2.0 * r1));
    float dlf1   = (float)dl1;
    r_normal *= 2.0;                              // 0.3
    float r2_2 = (float)(r_normal * r_normal);

    // cell sizes: r * 1.002 margin (superset coverage under f32 rounding)
    float cellA = (float)(0.075 * 1.002);
    float cellB = (float)(0.15  * 1.002);
    float cellC = (float)(0.3   * 1.002);

    dim3 bqgrid(NN / 64, BB);
    dim3 vxgrid(NN / 256, BB);
    dim3 vsgrid0((G0_3 + 255) / 256, BB);
    dim3 vsgrid1((G1_3 + 255) / 256, BB);

    hipMemsetAsync(histA, 0, (size_t)BB * (G3A + G3B + G3C) * sizeof(int), stream);
    prep_kernel<<<(int)((IN + 255) / 256), 256, 0, stream>>>(pts, dout);

    // grid A (supports = pts, r = 0.075)
    gcount_kernel<<<vxgrid, 256, 0, stream>>>(pts, nullptr, NN, cidA, histA, cellA, GA);
    gscan_kernel<<<BB, 1024, 0, stream>>>(histA, csA, curA, G3A);
    gscatter_kernel<<<vxgrid, 256, 0, stream>>>(pts, nullptr, NN, cidA, curA, sortedA, G3A);
    // layer 0
    bqg_kernel<<<bqgrid, 64, 0, stream>>>(pts, sortedA, csA, nullptr, NN,
                                          cellA, GA, out_neigh + 0 * IN, r2_0);
    vid_kernel<<<vxgrid, 256, 0, stream>>>(pts, nullptr, NN, vid0, dlf0, G0);
    vscan_kernel<<<vsgrid0, 256, 0, stream>>>(pts, vid0, nullptr, NN, vsum0, vcnt0, G0_3);
    compact_kernel<<<BB, 1024, 0, stream>>>(vsum0, vcnt0, G0_3, pts1, len1, out_len + 2);
    bqg_kernel<<<bqgrid, 64, 0, stream>>>(pts1, sortedA, csA, len1, 0,
                                          cellA, GA, out_pool + 0 * IN, r2_0);
    // grid B (supports = pts1, r = 0.15)
    gcount_kernel<<<vxgrid, 256, 0, stream>>>(pts1, len1, 0, cidB, histB, cellB, GB);
    gscan_kernel<<<BB, 1024, 0, stream>>>(histB, csB, curB, G3B);
    gscatter_kernel<<<vxgrid, 256, 0, stream>>>(pts1, len1, 0, cidB, curB, sortedB, G3B);
    bqg_kernel<<<bqgrid, 64, 0, stream>>>(pts, sortedB, csB, nullptr, NN,
                                          cellB, GB, out_up + 0 * IN, r2_up0);
    // layer 1
    vid_kernel<<<vxgrid, 256, 0, stream>>>(pts1, len1, 0, vid1, dlf1, G1);
    vscan_kernel<<<vsgrid1, 256, 0, stream>>>(pts1, vid1, len1, 0, vsum1, vcnt1, G1_3);
    compact_kernel<<<BB, 1024, 0, stream>>>(vsum1, vcnt1, G1_3, pts2, len2, out_len + 4);
    bqg_kernel<<<bqgrid, 64, 0, stream>>>(pts1, sortedB, csB, len1, 0,
                                          cellB, GB, out_neigh + 1 * IN, r2_1);
    bqg_kernel<<<bqgrid, 64, 0, stream>>>(pts2, sortedB, csB, len2, 0,
                                          cellB, GB, out_pool + 1 * IN, r2_1);
    // grid C (supports = pts2, r = 0.3)
    gcount_kernel<<<vxgrid, 256, 0, stream>>>(pts2, len2, 0, cidC, histC, cellC, GC);
    gscan_kernel<<<BB, 1024, 0, stream>>>(histC, csC, curC, G3C);
    gscatter_kernel<<<vxgrid, 256, 0, stream>>>(pts2, len2, 0, cidC, curC, sortedC, G3C);
    bqg_kernel<<<bqgrid, 64, 0, stream>>>(pts1, sortedC, csC, len1, 0,
                                          cellC, GC, out_up + 1 * IN, r2_up1);
    // layer 2
    bqg_kernel<<<bqgrid, 64, 0, stream>>>(pts2, sortedC, csC, len2, 0,
                                          cellC, GC, out_neigh + 2 * IN, r2_2);
}